// Round 1
// baseline (152.765 us; speedup 1.0000x reference)
//
#include <hip/hip_runtime.h>

#define T 128
#define DIMS 8
#define BIGF 1.0e10f
#define L2E 1.4426950408889634f   // log2(e)
#define LN2F 0.6931471805599453f  // ln(2)

// lane l <- lane (l-1) & 63  (DPP wave_ror:1, pure VALU, gfx9-family)
__device__ __forceinline__ float ror1(float x) {
    return __int_as_float(__builtin_amdgcn_update_dpp(
        __float_as_int(x), __float_as_int(x), 0x13C, 0xF, 0xF, false));
}

__launch_bounds__(256)
__global__ void sdtw_kernel(const float* __restrict__ X,
                            const float* __restrict__ Y,
                            float* __restrict__ out) {
    // per-wave LDS region: 128 rows * 12 floats (scaled -2*L2E*y) + 128 sqy
    __shared__ __align__(16) float lds[4 * 1664];
    const int lane = threadIdx.x & 63;
    const int w    = threadIdx.x >> 6;
    const int pair = blockIdx.x * 4 + w;   // 512 blocks * 4 waves = 2048 pairs
    const int a = pair >> 4;               // X index
    const int b = pair & 15;               // Y index

    float* ylds = lds + w * 1664;
    float* sqy  = ylds + 1536;

    // ---- stage Y[b], pre-scaled into log2 domain ----
    {
        const float* ybase = Y + (size_t)b * T * DIMS;
        for (int r = lane; r < T; r += 64) {
            const float4* src = (const float4*)(ybase + r * DIMS);
            float4 y0 = src[0], y1 = src[1];
            float s = y0.x*y0.x + y0.y*y0.y + y0.z*y0.z + y0.w*y0.w
                    + y1.x*y1.x + y1.y*y1.y + y1.z*y1.z + y1.w*y1.w;
            float* dst = ylds + r * 12;
            const float c = -2.0f * L2E;
            dst[0] = c*y0.x; dst[1] = c*y0.y; dst[2] = c*y0.z; dst[3] = c*y0.w;
            dst[4] = c*y1.x; dst[5] = c*y1.y; dst[6] = c*y1.z; dst[7] = c*y1.w;
            sqy[r] = L2E * s;
        }
    }

    // ---- X rows for this lane (rows lane and lane+64), raw values ----
    float x1[8], x2[8];
    float lsx1, lsx2;
    {
        const float* xb = X + ((size_t)a * T + lane) * DIMS;
        const float4* s0 = (const float4*)xb;
        float4 v0 = s0[0], v1 = s0[1];
        x1[0]=v0.x; x1[1]=v0.y; x1[2]=v0.z; x1[3]=v0.w;
        x1[4]=v1.x; x1[5]=v1.y; x1[6]=v1.z; x1[7]=v1.w;
        lsx1 = L2E*(v0.x*v0.x+v0.y*v0.y+v0.z*v0.z+v0.w*v0.w
                   +v1.x*v1.x+v1.y*v1.y+v1.z*v1.z+v1.w*v1.w);
        const float4* s1 = (const float4*)(xb + 64 * DIMS);
        float4 u0 = s1[0], u1 = s1[1];
        x2[0]=u0.x; x2[1]=u0.y; x2[2]=u0.z; x2[3]=u0.w;
        x2[4]=u1.x; x2[5]=u1.y; x2[6]=u1.z; x2[7]=u1.w;
        lsx2 = L2E*(u0.x*u0.x+u0.y*u0.y+u0.z*u0.z+u0.w*u0.w
                   +u1.x*u1.x+u1.y*u1.y+u1.z*u1.z+u1.w*u1.w);
    }

    __syncthreads();  // staging visible (once; DP loop is barrier-free)

    // DP state (scaled domain R' = R * log2e):
    // set1: row i=lane;  set2: row i=lane+64
    float p1a = BIGF, p2a = BIGF;  // prev diag (p-1), prev-prev (p-2), set1
    float p1b = BIGF, p2b = BIGF;  // set2

    for (int p = 0; p < 2 * T - 1; ++p) {
        // neighbor values from lane-1 via rotate
        float s1p1 = ror1(p1a);
        float s1p2 = ror1(p2a);
        float s2p1 = ror1(p1b);
        float s2p2 = ror1(p2b);
        const bool l0 = (lane == 0);
        const float corner = (p == 0) ? 0.0f : BIGF;

        // set1 cell (i=lane, j=p-lane)
        float A1 = l0 ? corner : s1p2;   // R[i-1][j-1]
        float B1 = l0 ? BIGF   : s1p1;   // R[i-1][j]
        float C1 = p1a;                  // R[i][j-1]
        // set2 cell (i=lane+64, j=p-64-lane); lane0 neighbors = set1 lane63 (= ror'd value)
        float A2 = l0 ? s1p2 : s2p2;
        float B2 = l0 ? s1p1 : s2p1;
        float C2 = p1b;

        int j1 = p - lane;
        int j2 = j1 - 64;
        int jj1 = min(max(j1, 0), T - 1);
        int jj2 = min(max(j2, 0), T - 1);

        // D * log2e via pre-scaled LDS rows
        const float* r1p = ylds + jj1 * 12;
        float4 ya = *(const float4*)r1p;
        float4 yb = *(const float4*)(r1p + 4);
        float acc1 = lsx1 + sqy[jj1];
        acc1 = fmaf(x1[0], ya.x, acc1); acc1 = fmaf(x1[1], ya.y, acc1);
        acc1 = fmaf(x1[2], ya.z, acc1); acc1 = fmaf(x1[3], ya.w, acc1);
        acc1 = fmaf(x1[4], yb.x, acc1); acc1 = fmaf(x1[5], yb.y, acc1);
        acc1 = fmaf(x1[6], yb.z, acc1); acc1 = fmaf(x1[7], yb.w, acc1);

        const float* r2p = ylds + jj2 * 12;
        float4 za = *(const float4*)r2p;
        float4 zb = *(const float4*)(r2p + 4);
        float acc2 = lsx2 + sqy[jj2];
        acc2 = fmaf(x2[0], za.x, acc2); acc2 = fmaf(x2[1], za.y, acc2);
        acc2 = fmaf(x2[2], za.z, acc2); acc2 = fmaf(x2[3], za.w, acc2);
        acc2 = fmaf(x2[4], zb.x, acc2); acc2 = fmaf(x2[5], zb.y, acc2);
        acc2 = fmaf(x2[6], zb.z, acc2); acc2 = fmaf(x2[7], zb.w, acc2);

        // softmin in log2 domain: m - log2(sum exp2(m - r))
        float m1 = fminf(fminf(A1, B1), C1);
        float e1 = exp2f(m1 - A1) + exp2f(m1 - B1) + exp2f(m1 - C1);
        float v1 = acc1 + (m1 - __log2f(e1));
        v1 = (j1 >= 0 && j1 < T) ? v1 : BIGF;

        float m2 = fminf(fminf(A2, B2), C2);
        float e2 = exp2f(m2 - A2) + exp2f(m2 - B2) + exp2f(m2 - C2);
        float v2 = acc2 + (m2 - __log2f(e2));
        v2 = (j2 >= 0 && j2 < T) ? v2 : BIGF;

        p2a = p1a; p1a = v1;
        p2b = p1b; p1b = v2;
    }

    // final cell (127,127) lives in set2, lane 63, after p = 254
    if (lane == 63) out[pair] = p1b * LN2F;
}

extern "C" void kernel_launch(void* const* d_in, const int* in_sizes, int n_in,
                              void* d_out, int out_size, void* d_ws, size_t ws_size,
                              hipStream_t stream) {
    const float* X = (const float*)d_in[0];   // (128,128,8) f32
    const float* Y = (const float*)d_in[1];   // (16,128,8) f32
    float* out = (float*)d_out;               // (128,16) f32
    sdtw_kernel<<<512, 256, 0, stream>>>(X, Y, out);
}

// Round 3
// 96.952 us; speedup vs baseline: 1.5757x; 1.5757x over previous
//
#include <hip/hip_runtime.h>

#define T 128
#define DIMS 8
#define L2E 1.4426950408889634f   // log2(e)
#define LN2F 0.6931471805599453f  // ln(2)

typedef _Float16 h2 __attribute__((ext_vector_type(2)));

// lane l <- lane (l-1) & 63  (DPP wave_ror:1)
__device__ __forceinline__ float ror1(float x) {
    return __int_as_float(__builtin_amdgcn_update_dpp(
        __float_as_int(x), __float_as_int(x), 0x13C, 0xF, 0xF, false));
}

template <int CTRL>
__device__ __forceinline__ float dppmax(float x) {
    float t = __int_as_float(__builtin_amdgcn_update_dpp(
        __float_as_int(x), __float_as_int(x), CTRL, 0xF, 0xF, false));
    return fmaxf(x, t);
}

__launch_bounds__(256)
__global__ void sdtw_kernel(const float* __restrict__ X,
                            const float* __restrict__ Y,
                            float* __restrict__ out) {
    // per-wave region: 130 rows * 4 floats (8 f16 y-values) + 130 sqy + pad
    __shared__ __align__(16) float lds[4 * 656];
    const int lane = threadIdx.x & 63;
    const int w    = threadIdx.x >> 6;
    const int pair = blockIdx.x * 4 + w;   // 512 blocks * 4 waves = 2048 pairs
    const int a = pair >> 4;               // X index
    const int b = pair & 15;               // Y index

    float* yw  = lds + w * 656;   // rows: m in [0,129], 16B each (8 f16)
    float* sqw = yw + 520;        // sqy', stride 1 (conflict-free)

    // ---- stage Y[b]: y' = 2*L2E*y as f16 pairs; sqy' = -L2E*|y|^2 ----
    {
        const float* ybase = Y + (size_t)b * T * DIMS;
        for (int r = lane; r < T; r += 64) {
            const float4* src = (const float4*)(ybase + r * DIMS);
            float4 y0 = src[0], y1 = src[1];
            float s = y0.x*y0.x + y0.y*y0.y + y0.z*y0.z + y0.w*y0.w
                    + y1.x*y1.x + y1.y*y1.y + y1.z*y1.z + y1.w*y1.w;
            const float c = 2.0f * L2E;
            h2 a0 = { (_Float16)(c*y0.x), (_Float16)(c*y0.y) };
            h2 a1 = { (_Float16)(c*y0.z), (_Float16)(c*y0.w) };
            h2 a2 = { (_Float16)(c*y1.x), (_Float16)(c*y1.y) };
            h2 a3 = { (_Float16)(c*y1.z), (_Float16)(c*y1.w) };
            float4 pk;
            pk.x = __builtin_bit_cast(float, a0);
            pk.y = __builtin_bit_cast(float, a1);
            pk.z = __builtin_bit_cast(float, a2);
            pk.w = __builtin_bit_cast(float, a3);
            *(float4*)(yw + ((r + 1) << 2)) = pk;
            sqw[r + 1] = -L2E * s;
        }
        if (lane < 2) {  // sentinel rows m=0 and m=129: E -> 0
            int m = lane ? 129 : 0;
            float4 z; z.x = 0.f; z.y = 0.f; z.z = 0.f; z.w = 0.f;
            *(float4*)(yw + (m << 2)) = z;
            sqw[m] = -3.0e37f;
        }
    }

    // ---- X rows for this lane (rows lane and lane+64) ----
    h2 x10, x11, x12, x13, x20, x21, x22, x23;
    float lsx1, lsx2;
    {
        const float* xb = X + ((size_t)a * T + lane) * DIMS;
        const float4* s0 = (const float4*)xb;
        float4 v0 = s0[0], v1 = s0[1];
        x10 = h2{ (_Float16)v0.x, (_Float16)v0.y };
        x11 = h2{ (_Float16)v0.z, (_Float16)v0.w };
        x12 = h2{ (_Float16)v1.x, (_Float16)v1.y };
        x13 = h2{ (_Float16)v1.z, (_Float16)v1.w };
        lsx1 = -L2E * (v0.x*v0.x+v0.y*v0.y+v0.z*v0.z+v0.w*v0.w
                      +v1.x*v1.x+v1.y*v1.y+v1.z*v1.z+v1.w*v1.w);
        const float4* s1 = (const float4*)(xb + 64 * DIMS);
        float4 u0 = s1[0], u1 = s1[1];
        x20 = h2{ (_Float16)u0.x, (_Float16)u0.y };
        x21 = h2{ (_Float16)u0.z, (_Float16)u0.w };
        x22 = h2{ (_Float16)u1.x, (_Float16)u1.y };
        x23 = h2{ (_Float16)u1.z, (_Float16)u1.w };
        lsx2 = -L2E * (u0.x*u0.x+u0.y*u0.y+u0.z*u0.z+u0.w*u0.w
                      +u1.x*u1.x+u1.y*u1.y+u1.z*u1.z+u1.w*u1.w);
    }

    __syncthreads();  // staging visible; DP loop is barrier-free

    const bool l0 = (lane == 0);

    // ---- p = 0: only cell (0,0); S = exp2(-D'(0,0)) * 2^90 ----
    float p1a, p2a = 0.f, p1b = 0.f, p2b = 0.f;
    int off = 90;
    {
        int m0 = min(max(1 - lane, 0), 129);   // lane0 -> row 1 (j=0), others sentinel
        float4 yv = *(const float4*)(yw + (m0 << 2));
        float acc = lsx1 + sqw[m0];
        acc = __builtin_amdgcn_fdot2(x10, __builtin_bit_cast(h2, yv.x), acc, false);
        acc = __builtin_amdgcn_fdot2(x11, __builtin_bit_cast(h2, yv.y), acc, false);
        acc = __builtin_amdgcn_fdot2(x12, __builtin_bit_cast(h2, yv.z), acc, false);
        acc = __builtin_amdgcn_fdot2(x13, __builtin_bit_cast(h2, yv.w), acc, false);
        p1a = __builtin_amdgcn_exp2f(acc) * 0x1p90f;  // lanes>0: E=0 -> 0
    }

    int jp1a = 2 - lane;     // j1+1 for p=1
    int jp1b = -62 - lane;   // j2+1 for p=1

#define BODY() {                                                              \
    float r1 = ror1(p1a), r2 = ror1(p2a);                                     \
    float q1 = ror1(p1b), q2 = ror1(p2b);                                     \
    float A1 = l0 ? 0.0f : r2;                                                \
    float B1 = l0 ? 0.0f : r1;                                                \
    float A2 = l0 ? r2 : q2;                                                  \
    float B2 = l0 ? r1 : q1;                                                  \
    int m1 = min(max(jp1a, 0), 129);                                          \
    int m2 = min(max(jp1b, 0), 129);                                          \
    float4 yv1 = *(const float4*)(yw + (m1 << 2));                            \
    float  sq1 = sqw[m1];                                                     \
    float4 yv2 = *(const float4*)(yw + (m2 << 2));                            \
    float  sq2 = sqw[m2];                                                     \
    float acc1 = lsx1 + sq1;                                                  \
    acc1 = __builtin_amdgcn_fdot2(x10, __builtin_bit_cast(h2, yv1.x), acc1, false); \
    acc1 = __builtin_amdgcn_fdot2(x11, __builtin_bit_cast(h2, yv1.y), acc1, false); \
    acc1 = __builtin_amdgcn_fdot2(x12, __builtin_bit_cast(h2, yv1.z), acc1, false); \
    acc1 = __builtin_amdgcn_fdot2(x13, __builtin_bit_cast(h2, yv1.w), acc1, false); \
    float acc2 = lsx2 + sq2;                                                  \
    acc2 = __builtin_amdgcn_fdot2(x20, __builtin_bit_cast(h2, yv2.x), acc2, false); \
    acc2 = __builtin_amdgcn_fdot2(x21, __builtin_bit_cast(h2, yv2.y), acc2, false); \
    acc2 = __builtin_amdgcn_fdot2(x22, __builtin_bit_cast(h2, yv2.z), acc2, false); \
    acc2 = __builtin_amdgcn_fdot2(x23, __builtin_bit_cast(h2, yv2.w), acc2, false); \
    float E1 = __builtin_amdgcn_exp2f(acc1);                                  \
    float E2 = __builtin_amdgcn_exp2f(acc2);                                  \
    float S1 = E1 * ((A1 + B1) + p1a);                                        \
    float S2 = E2 * ((A2 + B2) + p1b);                                        \
    p2a = p1a; p1a = S1;                                                      \
    p2b = p1b; p1b = S2;                                                      \
    ++jp1a; ++jp1b;                                                           \
}

#define RENORM() {                                                            \
    float mx = fmaxf(fmaxf(p1a, p1b), fmaxf(p2a, p2b));                       \
    mx = dppmax<0x111>(mx);  /* row_shr:1 */                                  \
    mx = dppmax<0x112>(mx);  /* row_shr:2 */                                  \
    mx = dppmax<0x114>(mx);  /* row_shr:4 */                                  \
    mx = dppmax<0x118>(mx);  /* row_shr:8 */                                  \
    /* lane 15+16r now holds max of row r; gather the 4 row maxima */         \
    int r0 = __builtin_amdgcn_readlane(__float_as_int(mx), 15);               \
    int r1_ = __builtin_amdgcn_readlane(__float_as_int(mx), 31);              \
    int r2_ = __builtin_amdgcn_readlane(__float_as_int(mx), 47);              \
    int r3 = __builtin_amdgcn_readlane(__float_as_int(mx), 63);               \
    int mb = max(max(r0, r1_), max(r2_, r3));  /* +floats: int order==float */\
    int e = ((mb >> 23) & 0xff) - 217;   /* exp-127-90: renorm max to 2^90 */ \
    p1a = ldexpf(p1a, -e); p2a = ldexpf(p2a, -e);                             \
    p1b = ldexpf(p1b, -e); p2b = ldexpf(p2b, -e);                             \
    off -= e;   /* S *= 2^-e  =>  off must drop by e to keep R' invariant */  \
}

    // p = 1 .. 252 in 63 groups of 4, renorm after each group
    for (int g = 0; g < 63; ++g) {
        BODY(); BODY(); BODY(); BODY();
        RENORM();
    }
    BODY();   // p = 253
    BODY();   // p = 254

    // final cell (127,127) in set2, lane 63: R' = off - log2(S); R = R'*ln2
    if (lane == 63)
        out[pair] = ((float)off - __builtin_amdgcn_logf(p1b)) * LN2F;
}

extern "C" void kernel_launch(void* const* d_in, const int* in_sizes, int n_in,
                              void* d_out, int out_size, void* d_ws, size_t ws_size,
                              hipStream_t stream) {
    const float* X = (const float*)d_in[0];   // (128,128,8) f32
    const float* Y = (const float*)d_in[1];   // (16,128,8) f32
    float* out = (float*)d_out;               // (128,16) f32
    sdtw_kernel<<<512, 256, 0, stream>>>(X, Y, out);
}

// Round 4
// 86.500 us; speedup vs baseline: 1.7661x; 1.1208x over previous
//
#include <hip/hip_runtime.h>

#define T 128
#define L2E 1.4426950408889634f   // log2(e)
#define LN2F 0.6931471805599453f  // ln(2)

typedef _Float16 h2 __attribute__((ext_vector_type(2)));

// lane l <- lane l-1; lane 0 <- 0   (DPP wave_shr:1, bound_ctrl=0)
__device__ __forceinline__ float shr1(float x) {
    return __int_as_float(__builtin_amdgcn_update_dpp(
        0, __float_as_int(x), 0x138, 0xF, 0xF, true));
}

template <int CTRL>
__device__ __forceinline__ float dppmax(float x) {
    float t = __int_as_float(__builtin_amdgcn_update_dpp(
        __float_as_int(x), __float_as_int(x), CTRL, 0xF, 0xF, false));
    return fmaxf(x, t);
}

struct Row { float2 u, v; float s; };   // 8 f16 y-values (packed) + f32 sq

__device__ __forceinline__ Row loadRow(const float* p) {
    Row r;
    r.u = *(const float2*)p;
    r.v = *(const float2*)(p + 2);
    r.s = p[4];
    return r;
}

__device__ __forceinline__ float dot2(h2 x, float ybits, float acc) {
    return __builtin_amdgcn_fdot2(x, __builtin_bit_cast(h2, ybits), acc, false);
}

__launch_bounds__(256)
__global__ void sdtw_kernel(const float* __restrict__ X,
                            const float* __restrict__ Y,
                            float* __restrict__ out) {
    // per-wave region: 384 rows * 6 dwords (24 B: 16 B f16-y, 4 B sq, 4 B pad)
    // row r holds y-row m = r - 125; valid m in [1,128]; rest sentinel (E=0)
    __shared__ __align__(16) float lds[4 * 2304];
    const int lane = threadIdx.x & 63;
    const int w    = threadIdx.x >> 6;
    const int pair = blockIdx.x * 4 + w;   // 512 blocks * 4 waves = 2048 pairs
    const int a = pair >> 4;               // X index
    const int b = pair & 15;               // Y index

    float* yw = lds + w * 2304;

    // ---- stage Y[b]: y' = 2*L2E*y (f16), sq = -L2E*|y|^2; sentinels elsewhere ----
    {
        const float* ybase = Y + (size_t)b * T * 8;
        for (int r = lane; r < 383; r += 64) {
            float4 pk; pk.x = 0.f; pk.y = 0.f; pk.z = 0.f; pk.w = 0.f;
            float sq = -3.0e37f;
            int j = r - 126;               // y row index for m = r-125 -> j = m-1
            if (j >= 0 && j < T) {
                const float4* src = (const float4*)(ybase + j * 8);
                float4 y0 = src[0], y1 = src[1];
                float s = y0.x*y0.x + y0.y*y0.y + y0.z*y0.z + y0.w*y0.w
                        + y1.x*y1.x + y1.y*y1.y + y1.z*y1.z + y1.w*y1.w;
                const float c = 2.0f * L2E;
                h2 a0 = { (_Float16)(c*y0.x), (_Float16)(c*y0.y) };
                h2 a1 = { (_Float16)(c*y0.z), (_Float16)(c*y0.w) };
                h2 a2 = { (_Float16)(c*y1.x), (_Float16)(c*y1.y) };
                h2 a3 = { (_Float16)(c*y1.z), (_Float16)(c*y1.w) };
                pk.x = __builtin_bit_cast(float, a0);
                pk.y = __builtin_bit_cast(float, a1);
                pk.z = __builtin_bit_cast(float, a2);
                pk.w = __builtin_bit_cast(float, a3);
                sq = -L2E * s;
            }
            float* dst = yw + r * 6;       // 24 B rows, 8-byte aligned
            float2 h; h.x = pk.x; h.y = pk.y;
            float2 g; g.x = pk.z; g.y = pk.w;
            *(float2*)dst = h;
            *(float2*)(dst + 2) = g;
            dst[4] = sq;
        }
    }

    // ---- X rows 2l (even) and 2l+1 (odd) for this lane ----
    h2 xe0, xe1, xe2, xe3, xo0, xo1, xo2, xo3;
    float lsxe, lsxo;
    {
        const float* xb = X + ((size_t)a * T + 2 * lane) * 8;
        const float4* s0 = (const float4*)xb;
        float4 v0 = s0[0], v1 = s0[1], u0 = s0[2], u1 = s0[3];
        xe0 = h2{ (_Float16)v0.x, (_Float16)v0.y };
        xe1 = h2{ (_Float16)v0.z, (_Float16)v0.w };
        xe2 = h2{ (_Float16)v1.x, (_Float16)v1.y };
        xe3 = h2{ (_Float16)v1.z, (_Float16)v1.w };
        lsxe = -L2E * (v0.x*v0.x+v0.y*v0.y+v0.z*v0.z+v0.w*v0.w
                      +v1.x*v1.x+v1.y*v1.y+v1.z*v1.z+v1.w*v1.w);
        xo0 = h2{ (_Float16)u0.x, (_Float16)u0.y };
        xo1 = h2{ (_Float16)u0.z, (_Float16)u0.w };
        xo2 = h2{ (_Float16)u1.x, (_Float16)u1.y };
        xo3 = h2{ (_Float16)u1.z, (_Float16)u1.w };
        lsxo = -L2E * (u0.x*u0.x+u0.y*u0.y+u0.z*u0.z+u0.w*u0.w
                      +u1.x*u1.x+u1.y*u1.y+u1.z*u1.z+u1.w*u1.w);
    }

    __syncthreads();

    // ---- prime the 4-slot row ring: ra=row(126-2l), rb=+1, rc=+2 ----
    Row ra = loadRow(yw + (126 - 2 * lane) * 6);
    Row rb = loadRow(yw + (127 - 2 * lane) * 6);
    Row rc = loadRow(yw + (128 - 2 * lane) * 6);
    Row rd;
    const float* fptr = yw + (129 - 2 * lane) * 6;   // fetch target for p=1

    // ---- p = 0: even cell (0,0) on lane 0 only (sentinels zero the rest) ----
    float fe0 = 0.f, fo0 = 0.f, fo1 = 0.f;
    int off = 90;
    float fe1;
    {
        float acc = lsxe + ra.s;
        acc = dot2(xe0, ra.u.x, acc);
        acc = dot2(xe1, ra.u.y, acc);
        acc = dot2(xe2, ra.v.x, acc);
        acc = dot2(xe3, ra.v.y, acc);
        fe1 = __builtin_amdgcn_exp2f(acc) * 0x1p90f;
    }

    // BODY: PE1/PO1 = p-1 state, PE2/PO2 = p-2 state (overwritten with new)
    // RO = odd row (m-1), RE = even row (m), RF = fetch dest (row m+2)
#define BODY(PE1, PE2, PO1, PO2, RO, RE, RF) {          \
    RF = loadRow(fptr); fptr += 6;                      \
    float sB = shr1(PO1);                               \
    float sA = shr1(PO2);                               \
    float ae = lsxe + RE.s;                             \
    ae = dot2(xe0, RE.u.x, ae);                         \
    ae = dot2(xe1, RE.u.y, ae);                         \
    ae = dot2(xe2, RE.v.x, ae);                         \
    ae = dot2(xe3, RE.v.y, ae);                         \
    float ao = lsxo + RO.s;                             \
    ao = dot2(xo0, RO.u.x, ao);                         \
    ao = dot2(xo1, RO.u.y, ao);                         \
    ao = dot2(xo2, RO.v.x, ao);                         \
    ao = dot2(xo3, RO.v.y, ao);                         \
    float Ee = __builtin_amdgcn_exp2f(ae);              \
    float Eo = __builtin_amdgcn_exp2f(ao);              \
    float Se = Ee * ((sA + sB) + PE1);                  \
    float So = Eo * ((PE2 + PE1) + PO1);                \
    PE2 = Se; PO2 = So;                                 \
}

#define RENORM() {                                                            \
    float mx = fmaxf(fmaxf(fe0, fe1), fmaxf(fo0, fo1));                       \
    mx = dppmax<0x111>(mx);  /* row_shr:1 */                                  \
    mx = dppmax<0x112>(mx);  /* row_shr:2 */                                  \
    mx = dppmax<0x114>(mx);  /* row_shr:4 */                                  \
    mx = dppmax<0x118>(mx);  /* row_shr:8 */                                  \
    int r0_ = __builtin_amdgcn_readlane(__float_as_int(mx), 15);              \
    int r1_ = __builtin_amdgcn_readlane(__float_as_int(mx), 31);              \
    int r2_ = __builtin_amdgcn_readlane(__float_as_int(mx), 47);              \
    int r3_ = __builtin_amdgcn_readlane(__float_as_int(mx), 63);              \
    int mb = max(max(r0_, r1_), max(r2_, r3_));                               \
    int e = ((mb >> 23) & 0xff) - 217;   /* renorm max to 2^90 */             \
    fe0 = ldexpf(fe0, -e); fe1 = ldexpf(fe1, -e);                             \
    fo0 = ldexpf(fo0, -e); fo1 = ldexpf(fo1, -e);                             \
    off -= e;                                                                 \
}

    // p = 1 .. 252: 63 groups of 4 (state swaps period-2, ring rotates period-4)
    for (int g = 0; g < 63; ++g) {
        BODY(fe1, fe0, fo1, fo0, ra, rb, rd);
        BODY(fe0, fe1, fo0, fo1, rb, rc, ra);
        BODY(fe1, fe0, fo1, fo0, rc, rd, rb);
        BODY(fe0, fe1, fo0, fo1, rd, ra, rc);
        RENORM();
    }
    BODY(fe1, fe0, fo1, fo0, ra, rb, rd);   // p = 253
    BODY(fe0, fe1, fo0, fo1, rb, rc, ra);   // p = 254 -> new p1o in fo1

    // final cell (127,127) = odd row of lane 63: R' = off - log2(S)
    if (lane == 63)
        out[pair] = ((float)off - __builtin_amdgcn_logf(fo1)) * LN2F;
}

extern "C" void kernel_launch(void* const* d_in, const int* in_sizes, int n_in,
                              void* d_out, int out_size, void* d_ws, size_t ws_size,
                              hipStream_t stream) {
    const float* X = (const float*)d_in[0];   // (128,128,8) f32
    const float* Y = (const float*)d_in[1];   // (16,128,8) f32
    float* out = (float*)d_out;               // (128,16) f32
    sdtw_kernel<<<512, 256, 0, stream>>>(X, Y, out);
}